// Round 2
// baseline (110.400 us; speedup 1.0000x reference)
//
#include <hip/hip_runtime.h>
#include <math.h>

// QuanvLayer1D collapsed form:
//   e_j(window) = sum_{b<=bp} Sc_j[m(b,bp)] * t_b * t_bp
//   t_b = prod_k (b_k ? sin(x_k/2) : cos(x_k/2))
//   Sc_j[m] = (b==bp ? 1 : 2) * sum_a sign_j(a) Re( conj(q_b[a]) q_bp[a] )
//   q_b = U3*U2*U1 * G^b * U0 |0>   (S_j is exactly symmetric)
// State layout per wave (64 lanes): amplitude a (8 bits) = r*64 + lane,
// qubit j <-> bit (7-j): qubit0 -> reg bit1, qubit1 -> reg bit0,
// qubits 2..7 -> lane masks 32,16,8,4,2,1.

#define DEV __device__ __forceinline__

#define NQ 8
#define LOUT 511
#define LIN 512
#define BS 32
#define NPAIR 136   // 16*17/2 packed symmetric pairs

DEV float sx(float v, int m) { return __shfl_xor(v, m, 64); }

// ---------- single-qubit rotations ----------
template<int J>
DEV void rot_rx(float (&re)[4], float (&im)[4], float c, float s) {
    if constexpr (J == 0) {            // pairs (0,2),(1,3)
        float r0=re[0], i0=im[0], r2=re[2], i2=im[2];
        re[0]=c*r0+s*i2; im[0]=c*i0-s*r2; re[2]=c*r2+s*i0; im[2]=c*i2-s*r0;
        float r1=re[1], i1=im[1], r3=re[3], i3=im[3];
        re[1]=c*r1+s*i3; im[1]=c*i1-s*r3; re[3]=c*r3+s*i1; im[3]=c*i3-s*r1;
    } else if constexpr (J == 1) {     // pairs (0,1),(2,3)
        float r0=re[0], i0=im[0], r1=re[1], i1=im[1];
        re[0]=c*r0+s*i1; im[0]=c*i0-s*r1; re[1]=c*r1+s*i0; im[1]=c*i1-s*r0;
        float r2=re[2], i2=im[2], r3=re[3], i3=im[3];
        re[2]=c*r2+s*i3; im[2]=c*i2-s*r3; re[3]=c*r3+s*i2; im[3]=c*i3-s*r2;
    } else {
        constexpr int m = 1 << (7 - J);
        #pragma unroll
        for (int r = 0; r < 4; ++r) {
            float pre = sx(re[r], m), pim = sx(im[r], m);
            re[r] = c*re[r] + s*pim;
            im[r] = c*im[r] - s*pre;
        }
    }
}

template<int J>
DEV void rot_ry(float (&re)[4], float (&im)[4], float c, float s, int lane) {
    if constexpr (J == 0) {
        float r0=re[0], i0=im[0], r2=re[2], i2=im[2];
        re[0]=c*r0-s*r2; im[0]=c*i0-s*i2; re[2]=s*r0+c*r2; im[2]=s*i0+c*i2;
        float r1=re[1], i1=im[1], r3=re[3], i3=im[3];
        re[1]=c*r1-s*r3; im[1]=c*i1-s*i3; re[3]=s*r1+c*r3; im[3]=s*i1+c*i3;
    } else if constexpr (J == 1) {
        float r0=re[0], i0=im[0], r1=re[1], i1=im[1];
        re[0]=c*r0-s*r1; im[0]=c*i0-s*i1; re[1]=s*r0+c*r1; im[1]=s*i0+c*i1;
        float r2=re[2], i2=im[2], r3=re[3], i3=im[3];
        re[2]=c*r2-s*r3; im[2]=c*i2-s*i3; re[3]=s*r2+c*r3; im[3]=s*i2+c*i3;
    } else {
        constexpr int m = 1 << (7 - J);
        float sg = (lane & m) ? s : -s;
        #pragma unroll
        for (int r = 0; r < 4; ++r) {
            float pre = sx(re[r], m), pim = sx(im[r], m);
            re[r] = c*re[r] + sg*pre;
            im[r] = c*im[r] + sg*pim;
        }
    }
}

template<int J>
DEV void rot_rz(float (&re)[4], float (&im)[4], float c, float s, int lane) {
    if constexpr (J == 0) {
        float t;
        t=re[0]; re[0]=c*t+s*im[0]; im[0]=c*im[0]-s*t;
        t=re[1]; re[1]=c*t+s*im[1]; im[1]=c*im[1]-s*t;
        t=re[2]; re[2]=c*t-s*im[2]; im[2]=c*im[2]+s*t;
        t=re[3]; re[3]=c*t-s*im[3]; im[3]=c*im[3]+s*t;
    } else if constexpr (J == 1) {
        float t;
        t=re[0]; re[0]=c*t+s*im[0]; im[0]=c*im[0]-s*t;
        t=re[2]; re[2]=c*t+s*im[2]; im[2]=c*im[2]-s*t;
        t=re[1]; re[1]=c*t-s*im[1]; im[1]=c*im[1]+s*t;
        t=re[3]; re[3]=c*t-s*im[3]; im[3]=c*im[3]+s*t;
    } else {
        constexpr int m = 1 << (7 - J);
        float sg = (lane & m) ? -s : s;
        #pragma unroll
        for (int r = 0; r < 4; ++r) {
            float t = re[r];
            re[r] = c*t + sg*im[r];
            im[r] = c*im[r] - sg*t;
        }
    }
}

// ---------- CNOT for wire J: (c,t) = (J, J+1) for J<7, (0,7) for J==7 ----------
template<int J>
DEV void cnot_w(float (&re)[4], float (&im)[4], int lane) {
    if constexpr (J == 0) {            // ctrl reg bit1, tgt reg bit0: swap r2<->r3
        float t;
        t=re[2]; re[2]=re[3]; re[3]=t;
        t=im[2]; im[2]=im[3]; im[3]=t;
    } else if constexpr (J == 1) {     // ctrl reg bit0 (r1,r3), tgt lane 32
        re[1]=sx(re[1],32); im[1]=sx(im[1],32);
        re[3]=sx(re[3],32); im[3]=sx(im[3],32);
    } else if constexpr (J == 7) {     // CNOT(0,7): ctrl reg bit1 (r2,r3), tgt lane 1
        re[2]=sx(re[2],1); im[2]=sx(im[2],1);
        re[3]=sx(re[3],1); im[3]=sx(im[3],1);
    } else {                           // ctrl lane 1<<(7-J), tgt lane 1<<(6-J)
        constexpr int mc = 1 << (7 - J);
        constexpr int mt = 1 << (6 - J);
        bool ctrl = (lane & mc) != 0;
        #pragma unroll
        for (int r = 0; r < 4; ++r) {
            float pre = sx(re[r], mt), pim = sx(im[r], mt);
            re[r] = ctrl ? pre : re[r];
            im[r] = ctrl ? pim : im[r];
        }
    }
}

template<int J>
DEV void wire(float (&re)[4], float (&im)[4], float ang, int lane) {
    float s, c;
    __sincosf(0.5f*ang, &s, &c);       // fast path: v_sin_f32 / v_cos_f32
    rot_rx<J>(re, im, c, s);
    cnot_w<J>(re, im, lane);
    rot_ry<J>(re, im, c, s, lane);
    cnot_w<J>(re, im, lane);
    rot_rz<J>(re, im, c, s, lane);
}

DEV void ansatz(float (&re)[4], float (&im)[4], const float* w, int lane) {
    wire<0>(re, im, w[0], lane);
    wire<1>(re, im, w[1], lane);
    wire<2>(re, im, w[2], lane);
    wire<3>(re, im, w[3], lane);
    wire<4>(re, im, w[4], lane);
    wire<5>(re, im, w[5], lane);
    wire<6>(re, im, w[6], lane);
    wire<7>(re, im, w[7], lane);
}

// ---------- fused kernel A: 16 waves, wave b computes q_b; then packed Sc ----------
__global__ __launch_bounds__(1024) void kA(const float* __restrict__ wts,
                                           float* __restrict__ Sc) {
    __shared__ float2 qlds[16 * 256];
    int tid  = threadIdx.x;
    int lane = tid & 63;
    int w    = tid >> 6;               // wave id == basis index b (0..15)

    float re[4] = {0.f,0.f,0.f,0.f}, im[4] = {0.f,0.f,0.f,0.f};
    if (lane == 0) re[0] = 1.0f;
    ansatz(re, im, wts, lane);

    // apply G on qubit k for each set bit k of b (wave-uniform branches)
    if (w & 1) {                       // qubit0: reg pairs (0,2),(1,3)
        float t;
        t=re[0]; re[0]=-re[2]; re[2]=t;  t=im[0]; im[0]=-im[2]; im[2]=t;
        t=re[1]; re[1]=-re[3]; re[3]=t;  t=im[1]; im[1]=-im[3]; im[3]=t;
    }
    if (w & 2) {                       // qubit1: reg pairs (0,1),(2,3)
        float t;
        t=re[0]; re[0]=-re[1]; re[1]=t;  t=im[0]; im[0]=-im[1]; im[1]=t;
        t=re[2]; re[2]=-re[3]; re[3]=t;  t=im[2]; im[2]=-im[3]; im[3]=t;
    }
    if (w & 4) {                       // qubit2: lane mask 32
        bool hi = (lane & 32) != 0;
        #pragma unroll
        for (int r = 0; r < 4; ++r) {
            float pre = sx(re[r],32), pim = sx(im[r],32);
            re[r] = hi ? pre : -pre;
            im[r] = hi ? pim : -pim;
        }
    }
    if (w & 8) {                       // qubit3: lane mask 16
        bool hi = (lane & 16) != 0;
        #pragma unroll
        for (int r = 0; r < 4; ++r) {
            float pre = sx(re[r],16), pim = sx(im[r],16);
            re[r] = hi ? pre : -pre;
            im[r] = hi ? pim : -pim;
        }
    }
    ansatz(re, im, wts + 8,  lane);
    ansatz(re, im, wts + 16, lane);
    ansatz(re, im, wts + 24, lane);
    #pragma unroll
    for (int r = 0; r < 4; ++r)
        qlds[w*256 + r*64 + lane] = make_float2(re[r], im[r]);
    __syncthreads();

    // phase 2: packed symmetric coefficients, pairs m = w, w+16, ...
    for (int m = w; m < NPAIR; m += 16) {
        int b = 0, rem = m;            // decode m -> (b, bp), b<=bp
        while (rem >= 16 - b) { rem -= 16 - b; ++b; }
        int bp = b + rem;

        float pp[4];
        #pragma unroll
        for (int rr = 0; rr < 4; ++rr) {
            float2 x = qlds[b *256 + rr*64 + lane];
            float2 y = qlds[bp*256 + rr*64 + lane];
            pp[rr] = x.x*y.x + x.y*y.y;
        }
        float a0  = (pp[0]+pp[1]) - (pp[2]+pp[3]);   // qubit0 (reg bit1)
        float a1  = (pp[0]+pp[2]) - (pp[1]+pp[3]);   // qubit1 (reg bit0)
        float tot =  pp[0]+pp[1]+pp[2]+pp[3];

        // plain butterfly sums for a0, a1
        #pragma unroll
        for (int mk = 1; mk <= 32; mk <<= 1) { a0 += sx(a0, mk); a1 += sx(a1, mk); }
        // Walsh-Hadamard on tot: lane L ends with sum_l (-1)^popcount(l&L) tot(l)
        #pragma unroll
        for (int mk = 1; mk <= 32; mk <<= 1) {
            float p = sx(tot, mk);
            tot = (lane & mk) ? (p - tot) : (tot + p);
        }
        float scale = (b == bp) ? 1.0f : 2.0f;
        if (lane == 0) { Sc[m*8+0] = scale*a0; Sc[m*8+1] = scale*a1; }
        if (lane == 32) Sc[m*8+2] = scale*tot;   // qubit2
        if (lane == 16) Sc[m*8+3] = scale*tot;   // qubit3
        if (lane ==  8) Sc[m*8+4] = scale*tot;   // qubit4
        if (lane ==  4) Sc[m*8+5] = scale*tot;   // qubit5
        if (lane ==  2) Sc[m*8+6] = scale*tot;   // qubit6
        if (lane ==  1) Sc[m*8+7] = scale*tot;   // qubit7
    }
}

// ---------- kernel B: per-window t, e_j = sum_m Sc[m][j] * t_b*t_bp ----------
__global__ __launch_bounds__(64) void kB(const float* __restrict__ vec,
                                         const float* __restrict__ Sc,
                                         float* __restrict__ out) {
    int lane = threadIdx.x;
    int o    = blockIdx.x * 64 + lane;  // 0..511
    int bat  = blockIdx.y;
    bool valid = o < LOUT;
    int oc = valid ? o : 0;

    float cs[4], sn[4];
    #pragma unroll
    for (int k = 0; k < 4; ++k) {
        int p = oc + k;                 // padded index 0..514
        float x = (p >= 1 && p <= LIN) ? vec[bat*LIN + p - 1] : 0.f;
        __sincosf(0.5f*x, &sn[k], &cs[k]);
    }
    float t[16];
    #pragma unroll
    for (int i = 0; i < 16; ++i)
        t[i] = ((i&1)?sn[0]:cs[0]) * ((i&2)?sn[1]:cs[1])
             * ((i&4)?sn[2]:cs[2]) * ((i&8)?sn[3]:cs[3]);

    float acc[8] = {0.f,0.f,0.f,0.f,0.f,0.f,0.f,0.f};
    int m = 0;
    #pragma unroll
    for (int b = 0; b < 16; ++b) {
        #pragma unroll
        for (int bp = b; bp < 16; ++bp) {
            float p = t[b] * t[bp];
            #pragma unroll
            for (int j = 0; j < 8; ++j)
                acc[j] = fmaf(Sc[m*8 + j], p, acc[j]);   // uniform -> s_load
            ++m;
        }
    }
    if (valid) {
        #pragma unroll
        for (int j = 0; j < 8; ++j)
            out[(bat*NQ + j)*LOUT + o] = acc[j];
    }
}

extern "C" void kernel_launch(void* const* d_in, const int* in_sizes, int n_in,
                              void* d_out, int out_size, void* d_ws, size_t ws_size,
                              hipStream_t stream) {
    const float* vec = (const float*)d_in[0];   // (32,1,512) f32
    const float* wts = (const float*)d_in[1];   // (4,8) f32
    float* out = (float*)d_out;                 // (32,8,511) f32
    float* Sc  = (float*)d_ws;                  // 136*8 f32 = 4352 B
    kA<<<1, 1024, 0, stream>>>(wts, Sc);
    kB<<<dim3(8, BS), 64, 0, stream>>>(vec, Sc, out);
}

// Round 3
// 77.548 us; speedup vs baseline: 1.4236x; 1.4236x over previous
//
#include <hip/hip_runtime.h>
#include <math.h>

// QuanvLayer1D collapsed form:
//   e_j(window) = sum_{b<=bp} Sc_j[m(b,bp)] * t_b * t_bp
//   t_b = prod_k (b_k ? sin(x_k/2) : cos(x_k/2))
//   Sc_j[m] = (b==bp ? 1 : 2) * sum_a sign_j(a) Re( conj(q_b[a]) q_bp[a] )
//   q_b = U3*U2*U1 * G^b * U0 |0>   (S_j is exactly symmetric)
// State layout per wave (64 lanes): amplitude a (8 bits) = r*64 + lane,
// qubit j <-> bit (7-j): qubit0 -> reg bit1, qubit1 -> reg bit0,
// qubits 2..7 -> lane masks 32,16,8,4,2,1.

#define DEV __device__ __forceinline__

#define NQ 8
#define LOUT 511
#define LIN 512
#define BS 32
#define NPAIR 136   // 16*17/2 packed symmetric pairs

DEV float sx(float v, int m) { return __shfl_xor(v, m, 64); }

// ---------- single-qubit rotations ----------
template<int J>
DEV void rot_rx(float (&re)[4], float (&im)[4], float c, float s) {
    if constexpr (J == 0) {            // pairs (0,2),(1,3)
        float r0=re[0], i0=im[0], r2=re[2], i2=im[2];
        re[0]=c*r0+s*i2; im[0]=c*i0-s*r2; re[2]=c*r2+s*i0; im[2]=c*i2-s*r0;
        float r1=re[1], i1=im[1], r3=re[3], i3=im[3];
        re[1]=c*r1+s*i3; im[1]=c*i1-s*r3; re[3]=c*r3+s*i1; im[3]=c*i3-s*r1;
    } else if constexpr (J == 1) {     // pairs (0,1),(2,3)
        float r0=re[0], i0=im[0], r1=re[1], i1=im[1];
        re[0]=c*r0+s*i1; im[0]=c*i0-s*r1; re[1]=c*r1+s*i0; im[1]=c*i1-s*r0;
        float r2=re[2], i2=im[2], r3=re[3], i3=im[3];
        re[2]=c*r2+s*i3; im[2]=c*i2-s*r3; re[3]=c*r3+s*i2; im[3]=c*i3-s*r2;
    } else {
        constexpr int m = 1 << (7 - J);
        #pragma unroll
        for (int r = 0; r < 4; ++r) {
            float pre = sx(re[r], m), pim = sx(im[r], m);
            re[r] = c*re[r] + s*pim;
            im[r] = c*im[r] - s*pre;
        }
    }
}

template<int J>
DEV void rot_ry(float (&re)[4], float (&im)[4], float c, float s, int lane) {
    if constexpr (J == 0) {
        float r0=re[0], i0=im[0], r2=re[2], i2=im[2];
        re[0]=c*r0-s*r2; im[0]=c*i0-s*i2; re[2]=s*r0+c*r2; im[2]=s*i0+c*i2;
        float r1=re[1], i1=im[1], r3=re[3], i3=im[3];
        re[1]=c*r1-s*r3; im[1]=c*i1-s*i3; re[3]=s*r1+c*r3; im[3]=s*i1+c*i3;
    } else if constexpr (J == 1) {
        float r0=re[0], i0=im[0], r1=re[1], i1=im[1];
        re[0]=c*r0-s*r1; im[0]=c*i0-s*i1; re[1]=s*r0+c*r1; im[1]=s*i0+c*i1;
        float r2=re[2], i2=im[2], r3=re[3], i3=im[3];
        re[2]=c*r2-s*r3; im[2]=c*i2-s*i3; re[3]=s*r2+c*r3; im[3]=s*i2+c*i3;
    } else {
        constexpr int m = 1 << (7 - J);
        float sg = (lane & m) ? s : -s;
        #pragma unroll
        for (int r = 0; r < 4; ++r) {
            float pre = sx(re[r], m), pim = sx(im[r], m);
            re[r] = c*re[r] + sg*pre;
            im[r] = c*im[r] + sg*pim;
        }
    }
}

template<int J>
DEV void rot_rz(float (&re)[4], float (&im)[4], float c, float s, int lane) {
    if constexpr (J == 0) {
        float t;
        t=re[0]; re[0]=c*t+s*im[0]; im[0]=c*im[0]-s*t;
        t=re[1]; re[1]=c*t+s*im[1]; im[1]=c*im[1]-s*t;
        t=re[2]; re[2]=c*t-s*im[2]; im[2]=c*im[2]+s*t;
        t=re[3]; re[3]=c*t-s*im[3]; im[3]=c*im[3]+s*t;
    } else if constexpr (J == 1) {
        float t;
        t=re[0]; re[0]=c*t+s*im[0]; im[0]=c*im[0]-s*t;
        t=re[2]; re[2]=c*t+s*im[2]; im[2]=c*im[2]-s*t;
        t=re[1]; re[1]=c*t-s*im[1]; im[1]=c*im[1]+s*t;
        t=re[3]; re[3]=c*t-s*im[3]; im[3]=c*im[3]+s*t;
    } else {
        constexpr int m = 1 << (7 - J);
        float sg = (lane & m) ? -s : s;
        #pragma unroll
        for (int r = 0; r < 4; ++r) {
            float t = re[r];
            re[r] = c*t + sg*im[r];
            im[r] = c*im[r] - sg*t;
        }
    }
}

// ---------- CNOT for wire J: (c,t) = (J, J+1) for J<7, (0,7) for J==7 ----------
template<int J>
DEV void cnot_w(float (&re)[4], float (&im)[4], int lane) {
    if constexpr (J == 0) {            // ctrl reg bit1, tgt reg bit0: swap r2<->r3
        float t;
        t=re[2]; re[2]=re[3]; re[3]=t;
        t=im[2]; im[2]=im[3]; im[3]=t;
    } else if constexpr (J == 1) {     // ctrl reg bit0 (r1,r3), tgt lane 32
        re[1]=sx(re[1],32); im[1]=sx(im[1],32);
        re[3]=sx(re[3],32); im[3]=sx(im[3],32);
    } else if constexpr (J == 7) {     // CNOT(0,7): ctrl reg bit1 (r2,r3), tgt lane 1
        re[2]=sx(re[2],1); im[2]=sx(im[2],1);
        re[3]=sx(re[3],1); im[3]=sx(im[3],1);
    } else {                           // ctrl lane 1<<(7-J), tgt lane 1<<(6-J)
        constexpr int mc = 1 << (7 - J);
        constexpr int mt = 1 << (6 - J);
        bool ctrl = (lane & mc) != 0;
        #pragma unroll
        for (int r = 0; r < 4; ++r) {
            float pre = sx(re[r], mt), pim = sx(im[r], mt);
            re[r] = ctrl ? pre : re[r];
            im[r] = ctrl ? pim : im[r];
        }
    }
}

template<int J>
DEV void wire(float (&re)[4], float (&im)[4], float c, float s, int lane) {
    rot_rx<J>(re, im, c, s);
    cnot_w<J>(re, im, lane);
    rot_ry<J>(re, im, c, s, lane);
    cnot_w<J>(re, im, lane);
    rot_rz<J>(re, im, c, s, lane);
}

// one ansatz layer, sincos precomputed (off = layer*8)
DEV void ansatz(float (&re)[4], float (&im)[4],
                const float (&C)[32], const float (&S)[32], int off, int lane) {
    wire<0>(re, im, C[off+0], S[off+0], lane);
    wire<1>(re, im, C[off+1], S[off+1], lane);
    wire<2>(re, im, C[off+2], S[off+2], lane);
    wire<3>(re, im, C[off+3], S[off+3], lane);
    wire<4>(re, im, C[off+4], S[off+4], lane);
    wire<5>(re, im, C[off+5], S[off+5], lane);
    wire<6>(re, im, C[off+6], S[off+6], lane);
    wire<7>(re, im, C[off+7], S[off+7], lane);
}

// ---------- kernel A1: q_b = U3*U2*U1 * G^b * U0 |0>, one b per block ----------
__global__ __launch_bounds__(64) void kA1(const float* __restrict__ wts,
                                          float2* __restrict__ q) {
    int lane = threadIdx.x;
    int b = blockIdx.x;                // 0..15
    // hoist all 32 sincos off the gate chain (independent, pipelined)
    float C[32], S[32];
    #pragma unroll
    for (int i = 0; i < 32; ++i) __sincosf(0.5f*wts[i], &S[i], &C[i]);

    float re[4] = {0.f,0.f,0.f,0.f}, im[4] = {0.f,0.f,0.f,0.f};
    if (lane == 0) re[0] = 1.0f;
    ansatz(re, im, C, S, 0, lane);

    // apply G on qubit k for each set bit k of b.  G: new_lo = -hi, new_hi = lo.
    if (b & 1) {                       // qubit0: reg pairs (0,2),(1,3)
        float t;
        t=re[0]; re[0]=-re[2]; re[2]=t;  t=im[0]; im[0]=-im[2]; im[2]=t;
        t=re[1]; re[1]=-re[3]; re[3]=t;  t=im[1]; im[1]=-im[3]; im[3]=t;
    }
    if (b & 2) {                       // qubit1: reg pairs (0,1),(2,3)
        float t;
        t=re[0]; re[0]=-re[1]; re[1]=t;  t=im[0]; im[0]=-im[1]; im[1]=t;
        t=re[2]; re[2]=-re[3]; re[3]=t;  t=im[2]; im[2]=-im[3]; im[3]=t;
    }
    if (b & 4) {                       // qubit2: lane mask 32
        bool hi = (lane & 32) != 0;
        #pragma unroll
        for (int r = 0; r < 4; ++r) {
            float pre = sx(re[r],32), pim = sx(im[r],32);
            re[r] = hi ? pre : -pre;
            im[r] = hi ? pim : -pim;
        }
    }
    if (b & 8) {                       // qubit3: lane mask 16
        bool hi = (lane & 16) != 0;
        #pragma unroll
        for (int r = 0; r < 4; ++r) {
            float pre = sx(re[r],16), pim = sx(im[r],16);
            re[r] = hi ? pre : -pre;
            im[r] = hi ? pim : -pim;
        }
    }
    ansatz(re, im, C, S, 8,  lane);
    ansatz(re, im, C, S, 16, lane);
    ansatz(re, im, C, S, 24, lane);
    #pragma unroll
    for (int r = 0; r < 4; ++r)
        q[b*256 + r*64 + lane] = make_float2(re[r], im[r]);
}

// ---------- kernel A2: one packed pair m=(b,bp) per block ----------
__global__ __launch_bounds__(64) void kA2(const float2* __restrict__ q,
                                          float* __restrict__ Sc) {
    int lane = threadIdx.x;
    int m = blockIdx.x;                // 0..135
    int b = 0, rem = m;                // decode m -> (b, bp), b<=bp
    while (rem >= 16 - b) { rem -= 16 - b; ++b; }
    int bp = b + rem;

    float pp[4];
    #pragma unroll
    for (int rr = 0; rr < 4; ++rr) {
        float2 x = q[b *256 + rr*64 + lane];
        float2 y = q[bp*256 + rr*64 + lane];
        pp[rr] = x.x*y.x + x.y*y.y;
    }
    float a0  = (pp[0]+pp[1]) - (pp[2]+pp[3]);   // qubit0 (reg bit1)
    float a1  = (pp[0]+pp[2]) - (pp[1]+pp[3]);   // qubit1 (reg bit0)
    float tot =  pp[0]+pp[1]+pp[2]+pp[3];

    // plain butterfly sums for a0, a1
    #pragma unroll
    for (int mk = 1; mk <= 32; mk <<= 1) { a0 += sx(a0, mk); a1 += sx(a1, mk); }
    // Walsh-Hadamard on tot: lane L ends with sum_l (-1)^popcount(l&L) tot(l)
    #pragma unroll
    for (int mk = 1; mk <= 32; mk <<= 1) {
        float p = sx(tot, mk);
        tot = (lane & mk) ? (p - tot) : (tot + p);
    }
    float scale = (b == bp) ? 1.0f : 2.0f;
    if (lane == 0) { Sc[m*8+0] = scale*a0; Sc[m*8+1] = scale*a1; }
    if (lane == 32) Sc[m*8+2] = scale*tot;   // qubit2
    if (lane == 16) Sc[m*8+3] = scale*tot;   // qubit3
    if (lane ==  8) Sc[m*8+4] = scale*tot;   // qubit4
    if (lane ==  4) Sc[m*8+5] = scale*tot;   // qubit5
    if (lane ==  2) Sc[m*8+6] = scale*tot;   // qubit6
    if (lane ==  1) Sc[m*8+7] = scale*tot;   // qubit7
}

// ---------- kernel B: per-window t, e_j = sum_m Sc[m][j] * t_b*t_bp ----------
__global__ __launch_bounds__(64) void kB(const float* __restrict__ vec,
                                         const float* __restrict__ Sc,
                                         float* __restrict__ out) {
    int lane = threadIdx.x;
    int o    = blockIdx.x * 64 + lane;  // 0..511
    int bat  = blockIdx.y;
    bool valid = o < LOUT;
    int oc = valid ? o : 0;

    float cs[4], sn[4];
    #pragma unroll
    for (int k = 0; k < 4; ++k) {
        int p = oc + k;                 // padded index 0..514
        float x = (p >= 1 && p <= LIN) ? vec[bat*LIN + p - 1] : 0.f;
        __sincosf(0.5f*x, &sn[k], &cs[k]);
    }
    float t[16];
    #pragma unroll
    for (int i = 0; i < 16; ++i)
        t[i] = ((i&1)?sn[0]:cs[0]) * ((i&2)?sn[1]:cs[1])
             * ((i&4)?sn[2]:cs[2]) * ((i&8)?sn[3]:cs[3]);

    float acc[8] = {0.f,0.f,0.f,0.f,0.f,0.f,0.f,0.f};
    int m = 0;
    #pragma unroll
    for (int b = 0; b < 16; ++b) {
        #pragma unroll
        for (int bp = b; bp < 16; ++bp) {
            float p = t[b] * t[bp];
            #pragma unroll
            for (int j = 0; j < 8; ++j)
                acc[j] = fmaf(Sc[m*8 + j], p, acc[j]);   // uniform -> s_load
            ++m;
        }
    }
    if (valid) {
        #pragma unroll
        for (int j = 0; j < 8; ++j)
            out[(bat*NQ + j)*LOUT + o] = acc[j];
    }
}

extern "C" void kernel_launch(void* const* d_in, const int* in_sizes, int n_in,
                              void* d_out, int out_size, void* d_ws, size_t ws_size,
                              hipStream_t stream) {
    const float* vec = (const float*)d_in[0];   // (32,1,512) f32
    const float* wts = (const float*)d_in[1];   // (4,8) f32
    float* out = (float*)d_out;                 // (32,8,511) f32
    float2* q  = (float2*)d_ws;                 // 16*256 complex = 32 KB
    float*  Sc = (float*)d_ws + 8192;           // 136*8 f32 = 4352 B
    kA1<<<16,  64, 0, stream>>>(wts, q);
    kA2<<<136, 64, 0, stream>>>(q, Sc);
    kB<<<dim3(8, BS), 64, 0, stream>>>(vec, Sc, out);
}